// Round 4
// baseline (468.113 us; speedup 1.0000x reference)
//
#include <hip/hip_runtime.h>
#include <hip/hip_cooperative_groups.h>

namespace cg = cooperative_groups;

#define BATCH 262144
#define EMB 300
#define NCHUNK 4096      // 64-pair chunks (== old NBLK)
#define GRID 256         // cooperative grid: 1 block per CU, guaranteed resident
// block = 1024 threads = 16 waves = 4 sub-groups of 256 threads.
// Each sub-group replicates one original 256-thread block verbatim;
// j-loop covers 4 chunks per sub-group: 256 blocks * 16 = 4096 chunks.

__global__ __launch_bounds__(1024, 4) void glove_fused(
    const int*   __restrict__ center,
    const int*   __restrict__ outside,
    const float* __restrict__ coocs,
    const float* __restrict__ weighting,
    const float* __restrict__ cemb,
    const float* __restrict__ oemb,
    const float* __restrict__ cbias,
    const float* __restrict__ obias,
    float*       __restrict__ block_sums,
    float*       __restrict__ out)
{
    const int tid  = threadIdx.x;
    const int warp = tid >> 6;        // 0..15
    const int lane = tid & 63;
    const int l    = lane & 15;       // lane within 16-lane pair-group
    const int g    = lane >> 4;       // pair-group 0..3
    const int sub  = warp >> 2;       // sub-group 0..3 (plays "old block")
    const int wsub = warp & 3;        // warp within sub-group (old "warp")

    __shared__ float smem[4][4];

    for (int j = 0; j < 4; ++j) {
        // chunk == old blockIdx; base identical to old (bid*4+warp)*16+g
        const int chunk = (int)blockIdx.x * 16 + j * 4 + sub;
        const int base  = chunk * 64 + wsub * 16 + g;

        int ci[4], oi[4];
        #pragma unroll
        for (int it = 0; it < 4; ++it) {
            ci[it] = center[base + it * 4];
            oi[it] = outside[base + it * 4];
        }

        // double-buffered stage registers (baseline-verbatim)
        float4 sa[2][5], sb[2][5];
        float  scb[2], sob[2], scc[2], swt[2];

        #pragma unroll
        for (int s = 0; s < 2; ++s) {
            const float4* __restrict__ A = (const float4*)(cemb + (long)ci[s] * EMB);
            const float4* __restrict__ B = (const float4*)(oemb + (long)oi[s] * EMB);
            #pragma unroll
            for (int i = 0; i < 4; ++i) {
                sa[s][i] = A[i * 16 + l];
                sb[s][i] = B[i * 16 + l];
            }
            sa[s][4].x = 0.f; sa[s][4].y = 0.f; sa[s][4].z = 0.f; sa[s][4].w = 0.f;
            sb[s][4] = sa[s][4];
            if (l < 11) {              // 75 float4/row: lanes 0..10 cover [64,75)
                sa[s][4] = A[64 + l];
                sb[s][4] = B[64 + l];
            }
            scb[s] = cbias[ci[s]];
            sob[s] = obias[oi[s]];
            scc[s] = coocs[base + s * 4];
            swt[s] = weighting[base + s * 4];
        }

        float local = 0.0f;

        #pragma unroll
        for (int it = 0; it < 4; ++it) {
            const int buf = it & 1;

            float s = 0.f;
            #pragma unroll
            for (int i = 0; i < 5; ++i) {
                s += sa[buf][i].x * sb[buf][i].x + sa[buf][i].y * sb[buf][i].y
                   + sa[buf][i].z * sb[buf][i].z + sa[buf][i].w * sb[buf][i].w;
            }
            const float cbv = scb[buf], obv = sob[buf], ccv = scc[buf], wtv = swt[buf];

            if (it + 2 < 4) {
                const int n = it + 2;
                const float4* __restrict__ A = (const float4*)(cemb + (long)ci[n] * EMB);
                const float4* __restrict__ B = (const float4*)(oemb + (long)oi[n] * EMB);
                #pragma unroll
                for (int i = 0; i < 4; ++i) {
                    sa[buf][i] = A[i * 16 + l];
                    sb[buf][i] = B[i * 16 + l];
                }
                if (l < 11) {
                    sa[buf][4] = A[64 + l];
                    sb[buf][4] = B[64 + l];
                } else {
                    sa[buf][4].x = 0.f; sa[buf][4].y = 0.f; sa[buf][4].z = 0.f; sa[buf][4].w = 0.f;
                    sb[buf][4] = sa[buf][4];
                }
                scb[buf] = cbias[ci[n]];
                sob[buf] = obias[oi[n]];
                scc[buf] = coocs[base + n * 4];
                swt[buf] = weighting[base + n * 4];
            }

            // 4-step butterfly within the 16-lane group
            s += __shfl_xor(s, 1);
            s += __shfl_xor(s, 2);
            s += __shfl_xor(s, 4);
            s += __shfl_xor(s, 8);

            if (l == 0) {
                const float e = s + cbv + obv - ccv;
                local += wtv * e * e;
            }
        }

        // gather the 4 group-leaders (lanes 0,16,32,48) to lane 0 of each wave
        local += __shfl_down(local, 32, 64);
        local += __shfl_down(local, 16, 64);

        if (lane == 0) smem[sub][wsub] = local;
        __syncthreads();
        if (wsub == 0 && lane == 0)    // tid == sub*256: old "tid==0"
            block_sums[chunk] = smem[sub][0] + smem[sub][1] + smem[sub][2] + smem[sub][3];
        __syncthreads();               // protect smem reuse next j
    }

    __threadfence();                   // make block_sums globally visible
    cg::this_grid().sync();

    // ---- final reduce: block 0's 1024 threads run glove_reduce verbatim ----
    if (blockIdx.x == 0) {
        const int t = tid;
        float4 v = ((const float4*)block_sums)[t];   // 1024 x 4 = 4096 partials
        float s = v.x + v.y + v.z + v.w;
        #pragma unroll
        for (int off = 32; off > 0; off >>= 1)
            s += __shfl_down(s, off, 64);
        __shared__ float sm[16];
        if ((t & 63) == 0) sm[t >> 6] = s;
        __syncthreads();
        if (t < 16) {
            float x = sm[t];
            #pragma unroll
            for (int off = 8; off > 0; off >>= 1)
                x += __shfl_down(x, off, 16);
            if (t == 0) out[0] = x;
        }
    }
}

// ------------------------------------------------------------------
// Non-cooperative fallback (baseline, verified 303 us) in case the
// device/runtime rejects cooperative launch.
// ------------------------------------------------------------------
#define NBLK 4096
#define WPB 4

__global__ __launch_bounds__(256) void glove_main(
    const int*   __restrict__ center,
    const int*   __restrict__ outside,
    const float* __restrict__ coocs,
    const float* __restrict__ weighting,
    const float* __restrict__ cemb,
    const float* __restrict__ oemb,
    const float* __restrict__ cbias,
    const float* __restrict__ obias,
    float*       __restrict__ block_sums)
{
    const int tid  = threadIdx.x;
    const int warp = tid >> 6;
    const int lane = tid & 63;
    const int l    = lane & 15;
    const int g    = lane >> 4;
    const int base = (blockIdx.x * WPB + warp) * 16 + g;

    int ci[4], oi[4];
    #pragma unroll
    for (int it = 0; it < 4; ++it) {
        ci[it] = center[base + it * 4];
        oi[it] = outside[base + it * 4];
    }

    float4 sa[2][5], sb[2][5];
    float  scb[2], sob[2], scc[2], swt[2];

    #pragma unroll
    for (int s = 0; s < 2; ++s) {
        const float4* __restrict__ A = (const float4*)(cemb + (long)ci[s] * EMB);
        const float4* __restrict__ B = (const float4*)(oemb + (long)oi[s] * EMB);
        #pragma unroll
        for (int i = 0; i < 4; ++i) {
            sa[s][i] = A[i * 16 + l];
            sb[s][i] = B[i * 16 + l];
        }
        sa[s][4].x = 0.f; sa[s][4].y = 0.f; sa[s][4].z = 0.f; sa[s][4].w = 0.f;
        sb[s][4] = sa[s][4];
        if (l < 11) {
            sa[s][4] = A[64 + l];
            sb[s][4] = B[64 + l];
        }
        scb[s] = cbias[ci[s]];
        sob[s] = obias[oi[s]];
        scc[s] = coocs[base + s * 4];
        swt[s] = weighting[base + s * 4];
    }

    float local = 0.0f;

    #pragma unroll
    for (int it = 0; it < 4; ++it) {
        const int buf = it & 1;

        float s = 0.f;
        #pragma unroll
        for (int i = 0; i < 5; ++i) {
            s += sa[buf][i].x * sb[buf][i].x + sa[buf][i].y * sb[buf][i].y
               + sa[buf][i].z * sb[buf][i].z + sa[buf][i].w * sb[buf][i].w;
        }
        const float cbv = scb[buf], obv = sob[buf], ccv = scc[buf], wtv = swt[buf];

        if (it + 2 < 4) {
            const int n = it + 2;
            const float4* __restrict__ A = (const float4*)(cemb + (long)ci[n] * EMB);
            const float4* __restrict__ B = (const float4*)(oemb + (long)oi[n] * EMB);
            #pragma unroll
            for (int i = 0; i < 4; ++i) {
                sa[buf][i] = A[i * 16 + l];
                sb[buf][i] = B[i * 16 + l];
            }
            if (l < 11) {
                sa[buf][4] = A[64 + l];
                sb[buf][4] = B[64 + l];
            } else {
                sa[buf][4].x = 0.f; sa[buf][4].y = 0.f; sa[buf][4].z = 0.f; sa[buf][4].w = 0.f;
                sb[buf][4] = sa[buf][4];
            }
            scb[buf] = cbias[ci[n]];
            sob[buf] = obias[oi[n]];
            scc[buf] = coocs[base + n * 4];
            swt[buf] = weighting[base + n * 4];
        }

        s += __shfl_xor(s, 1);
        s += __shfl_xor(s, 2);
        s += __shfl_xor(s, 4);
        s += __shfl_xor(s, 8);

        if (l == 0) {
            const float e = s + cbv + obv - ccv;
            local += wtv * e * e;
        }
    }

    local += __shfl_down(local, 32, 64);
    local += __shfl_down(local, 16, 64);

    __shared__ float smem[WPB];
    if (lane == 0) smem[warp] = local;
    __syncthreads();
    if (tid == 0)
        block_sums[blockIdx.x] = smem[0] + smem[1] + smem[2] + smem[3];
}

__global__ __launch_bounds__(1024) void glove_reduce(
    const float* __restrict__ part, float* __restrict__ out)
{
    const int t = threadIdx.x;
    float4 v = ((const float4*)part)[t];          // 1024 x 4 = 4096 partials
    float s = v.x + v.y + v.z + v.w;
    #pragma unroll
    for (int off = 32; off > 0; off >>= 1)
        s += __shfl_down(s, off, 64);
    __shared__ float sm[16];
    if ((t & 63) == 0) sm[t >> 6] = s;
    __syncthreads();
    if (t < 16) {
        float x = sm[t];
        #pragma unroll
        for (int off = 8; off > 0; off >>= 1)
            x += __shfl_down(x, off, 16);
        if (t == 0) out[0] = x;
    }
}

extern "C" void kernel_launch(void* const* d_in, const int* in_sizes, int n_in,
                              void* d_out, int out_size, void* d_ws, size_t ws_size,
                              hipStream_t stream) {
    const int*   center    = (const int*)  d_in[0];
    const int*   outside   = (const int*)  d_in[1];
    const float* coocs     = (const float*)d_in[2];
    const float* weighting = (const float*)d_in[3];
    const float* cemb      = (const float*)d_in[4];
    const float* oemb      = (const float*)d_in[5];
    const float* cbias     = (const float*)d_in[6];
    const float* obias     = (const float*)d_in[7];
    float* out        = (float*)d_out;
    float* block_sums = (float*)d_ws;   // NCHUNK floats = 16 KB, fully overwritten

    static int coop_ok = -1;            // host-side query, no stream ops
    if (coop_ok < 0) {
        int v = 0;
        hipDeviceGetAttribute(&v, hipDeviceAttributeCooperativeLaunch, 0);
        coop_ok = v;
    }

    if (coop_ok) {
        void* args[] = {
            (void*)&center, (void*)&outside, (void*)&coocs, (void*)&weighting,
            (void*)&cemb, (void*)&oemb, (void*)&cbias, (void*)&obias,
            (void*)&block_sums, (void*)&out
        };
        hipLaunchCooperativeKernel((const void*)glove_fused,
                                   dim3(GRID), dim3(1024), args, 0, stream);
    } else {
        glove_main  <<<NBLK, 256, 0, stream>>>(
            center, outside, coocs, weighting, cemb, oemb, cbias, obias, block_sums);
        glove_reduce<<<1, 1024, 0, stream>>>(block_sums, out);
    }
}